// Round 1
// baseline (117.871 us; speedup 1.0000x reference)
//
#include <hip/hip_runtime.h>

typedef float f32x4 __attribute__((ext_vector_type(4)));
typedef __bf16 bf16x8 __attribute__((ext_vector_type(8)));
typedef __bf16 bf16x4 __attribute__((ext_vector_type(4)));

#define B_ 8
#define T_ 2048
#define DE 1024
#define DQ 64
#define SCALE 0.125f

// ---------- kernel 0: Wt[n][k] = W[k][n] as bf16, n in [0,192), k in [0,1024)
__global__ __launch_bounds__(256) void kw_transpose(
    const float* __restrict__ Wq, const float* __restrict__ Wk,
    const float* __restrict__ Wv, __bf16* __restrict__ Wt)
{
  int idx = blockIdx.x * 256 + threadIdx.x;     // 0 .. 196607
  int n = idx >> 10, k = idx & 1023;
  const float* W = (n < 64) ? Wq : ((n < 128) ? Wk : Wv);
  Wt[idx] = (__bf16)W[k * 64 + (n & 63)];
}

// ---------- kernel 1: QKV projection.  Q,K row-major bf16 [16384][64]; V transposed [8][64][2048]
__global__ __launch_bounds__(256) void kproj(
    const float* __restrict__ x, const __bf16* __restrict__ Wt,
    __bf16* __restrict__ Qb, __bf16* __restrict__ Kb, __bf16* __restrict__ Vt)
{
  const int lane = threadIdx.x & 63;
  const int widx = threadIdx.x >> 6;
  const int col = lane & 15, g = lane >> 4;
  const int mbase = (blockIdx.x * 4 + widx) * 16;

  f32x4 acc[12];
#pragma unroll
  for (int i = 0; i < 12; ++i) acc[i] = (f32x4){0.f, 0.f, 0.f, 0.f};

  const float* xrow = x + (size_t)(mbase + col) * DE + g * 8;
#pragma unroll 2
  for (int kk = 0; kk < DE; kk += 32) {
    f32x4 a0 = *(const f32x4*)(xrow + kk);
    f32x4 a1 = *(const f32x4*)(xrow + kk + 4);
    bf16x8 af;
#pragma unroll
    for (int j = 0; j < 4; ++j) { af[j] = (__bf16)a0[j]; af[4 + j] = (__bf16)a1[j]; }
#pragma unroll
    for (int i = 0; i < 12; ++i) {
      bf16x8 bf = *(const bf16x8*)(Wt + (size_t)(i * 16 + col) * DE + kk + g * 8);
      acc[i] = __builtin_amdgcn_mfma_f32_16x16x32_bf16(af, bf, acc[i], 0, 0, 0);
    }
  }

  // epilogue: D layout: row = g*4 + r, col = tile*16 + (lane&15)
  const int b = mbase >> 11;
  const int t0 = (mbase & 2047) + g * 4;
#pragma unroll
  for (int i = 0; i < 8; ++i) {
    __bf16* dst = (i < 4) ? Qb : Kb;
    int c = (i & 3) * 16 + col;
#pragma unroll
    for (int r = 0; r < 4; ++r) {
      int m = mbase + g * 4 + r;
      dst[(size_t)m * DQ + c] = (__bf16)acc[i][r];
    }
  }
#pragma unroll
  for (int i = 8; i < 12; ++i) {
    int d = (i - 8) * 16 + col;
    bf16x4 v;
#pragma unroll
    for (int r = 0; r < 4; ++r) v[r] = (__bf16)acc[i][r];
    *(bf16x4*)(Vt + ((size_t)(b * DQ + d)) * T_ + t0) = v;
  }
}

// ---------- kernel 2: causal flash attention, one wave = 16 Q rows, KVBLK = 32
__global__ __launch_bounds__(256) void kattn(
    const __bf16* __restrict__ Qb, const __bf16* __restrict__ Kb,
    const __bf16* __restrict__ Vt, float* __restrict__ out)
{
  __shared__ __bf16 plds[4][16][40];          // padded: 80B rows -> 16B aligned, 2-way banks
  const int lane = threadIdx.x & 63;
  const int widx = threadIdx.x >> 6;
  const int col = lane & 15, g = lane >> 4;
  const int b = blockIdx.x >> 5;              // 32 blocks per batch
  const int jq = (blockIdx.x & 31) + widx * 32;   // qtile 0..127, balanced per block
  const int qbase = jq * 16;

  const __bf16* Qp = Qb + (size_t)(b * T_ + qbase) * DQ + (size_t)col * DQ + g * 8;
  bf16x8 q0 = *(const bf16x8*)(Qp);
  bf16x8 q1 = *(const bf16x8*)(Qp + 32);

  const __bf16* Kbb = Kb + (size_t)b * T_ * DQ;
  const __bf16* Vbb = Vt + (size_t)b * DQ * T_;

  f32x4 acc0 = {0.f,0.f,0.f,0.f}, acc1 = {0.f,0.f,0.f,0.f};
  f32x4 acc2 = {0.f,0.f,0.f,0.f}, acc3 = {0.f,0.f,0.f,0.f};
  float mrun[4], lsum[4];
#pragma unroll
  for (int r = 0; r < 4; ++r) { mrun[r] = -1e30f; lsum[r] = 0.f; }

  const int nb = (jq >> 1) + 1;               // ceil((qbase+16)/32)
  for (int it = 0; it < nb; ++it) {
    const int nbase = it * 32;
    const __bf16* Kp = Kbb + (size_t)(nbase + col) * DQ + g * 8;
    bf16x8 k00 = *(const bf16x8*)(Kp);
    bf16x8 k01 = *(const bf16x8*)(Kp + 32);
    bf16x8 k10 = *(const bf16x8*)(Kp + 16 * DQ);
    bf16x8 k11 = *(const bf16x8*)(Kp + 16 * DQ + 32);

    f32x4 s0 = {0.f,0.f,0.f,0.f}, s1 = {0.f,0.f,0.f,0.f};
    s0 = __builtin_amdgcn_mfma_f32_16x16x32_bf16(q0, k00, s0, 0, 0, 0);
    s0 = __builtin_amdgcn_mfma_f32_16x16x32_bf16(q1, k01, s0, 0, 0, 0);
    s1 = __builtin_amdgcn_mfma_f32_16x16x32_bf16(q0, k10, s1, 0, 0, 0);
    s1 = __builtin_amdgcn_mfma_f32_16x16x32_bf16(q1, k11, s1, 0, 0, 0);

    float p0[4], p1[4];
#pragma unroll
    for (int r = 0; r < 4; ++r) { p0[r] = s0[r] * SCALE; p1[r] = s1[r] * SCALE; }

    if (it == nb - 1) {                        // causal mask (only last block touches diagonal)
#pragma unroll
      for (int r = 0; r < 4; ++r) {
        int m = qbase + g * 4 + r;
        if (nbase + col > m)      p0[r] = -1e30f;
        if (nbase + 16 + col > m) p1[r] = -1e30f;
      }
    }

    float mv[4];
#pragma unroll
    for (int r = 0; r < 4; ++r) mv[r] = fmaxf(p0[r], p1[r]);
#pragma unroll
    for (int sh = 1; sh <= 8; sh <<= 1) {
#pragma unroll
      for (int r = 0; r < 4; ++r) mv[r] = fmaxf(mv[r], __shfl_xor(mv[r], sh, 64));
    }

    float rs[4];
#pragma unroll
    for (int r = 0; r < 4; ++r) {
      float mn = fmaxf(mrun[r], mv[r]);
      rs[r] = __expf(mrun[r] - mn);
      mrun[r] = mn;
      p0[r] = __expf(p0[r] - mn);
      p1[r] = __expf(p1[r] - mn);
      lsum[r] = lsum[r] * rs[r] + p0[r] + p1[r];
    }
#pragma unroll
    for (int r = 0; r < 4; ++r) {
      acc0[r] *= rs[r]; acc1[r] *= rs[r]; acc2[r] *= rs[r]; acc3[r] *= rs[r];
      plds[widx][g * 4 + r][col]      = (__bf16)p0[r];
      plds[widx][g * 4 + r][16 + col] = (__bf16)p1[r];
    }

    // D-layout -> A-layout via LDS (wave-private, compiler inserts lgkmcnt waits)
    bf16x8 pf = *(const bf16x8*)&plds[widx][col][g * 8];

    const __bf16* Vp = Vbb + (size_t)col * T_ + nbase + g * 8;
    bf16x8 v0 = *(const bf16x8*)(Vp);
    bf16x8 v1 = *(const bf16x8*)(Vp + 16 * T_);
    bf16x8 v2 = *(const bf16x8*)(Vp + 32 * T_);
    bf16x8 v3 = *(const bf16x8*)(Vp + 48 * T_);

    acc0 = __builtin_amdgcn_mfma_f32_16x16x32_bf16(pf, v0, acc0, 0, 0, 0);
    acc1 = __builtin_amdgcn_mfma_f32_16x16x32_bf16(pf, v1, acc1, 0, 0, 0);
    acc2 = __builtin_amdgcn_mfma_f32_16x16x32_bf16(pf, v2, acc2, 0, 0, 0);
    acc3 = __builtin_amdgcn_mfma_f32_16x16x32_bf16(pf, v3, acc3, 0, 0, 0);
  }

  // final row-sum reduce + normalize + write fp32 out
#pragma unroll
  for (int sh = 1; sh <= 8; sh <<= 1) {
#pragma unroll
    for (int r = 0; r < 4; ++r) lsum[r] += __shfl_xor(lsum[r], sh, 64);
  }

  float* op = out + (size_t)(b * T_ + qbase) * DQ;
#pragma unroll
  for (int r = 0; r < 4; ++r) {
    float inv = 1.f / lsum[r];
    int m = g * 4 + r;
    op[(size_t)m * DQ + col]      = acc0[r] * inv;
    op[(size_t)m * DQ + 16 + col] = acc1[r] * inv;
    op[(size_t)m * DQ + 32 + col] = acc2[r] * inv;
    op[(size_t)m * DQ + 48 + col] = acc3[r] * inv;
  }
}

extern "C" void kernel_launch(void* const* d_in, const int* in_sizes, int n_in,
                              void* d_out, int out_size, void* d_ws, size_t ws_size,
                              hipStream_t stream)
{
  const float* x  = (const float*)d_in[0];
  const float* Wq = (const float*)d_in[1];
  const float* Wk = (const float*)d_in[2];
  const float* Wv = (const float*)d_in[3];
  float* out = (float*)d_out;

  char* ws = (char*)d_ws;
  __bf16* Wt = (__bf16*)(ws);                                   // 384 KiB
  __bf16* Qb = (__bf16*)(ws + 0x80000);                         // 2 MiB
  __bf16* Kb = (__bf16*)(ws + 0x80000 + 0x200000);              // 2 MiB
  __bf16* Vt = (__bf16*)(ws + 0x80000 + 0x400000);              // 2 MiB

  kw_transpose<<<768, 256, 0, stream>>>(Wq, Wk, Wv, Wt);
  kproj<<<256, 256, 0, stream>>>(x, Wt, Qb, Kb, Vt);
  kattn<<<256, 256, 0, stream>>>(Qb, Kb, Vt, out);
}